// Round 13
// baseline (207.942 us; speedup 1.0000x reference)
//
#include <hip/hip_runtime.h>
#include <hip/hip_bf16.h>

typedef __bf16 bf16x8 __attribute__((ext_vector_type(8)));
typedef float  f32x4  __attribute__((ext_vector_type(4)));
typedef short  short8 __attribute__((ext_vector_type(8)));
typedef float  f32x4v __attribute__((ext_vector_type(4)));

#define B_SZ 4
#define N_SZ 16384
#define DIM_SZ 384
#define H_SZ 8
#define C_SZ 48
#define M_SZ 24

static constexpr float SCALE = 0.37991784282579627f;   // 48^-0.25
static constexpr float RSM   = 0.20412414523193154f;   // 1/sqrt(24)
static constexpr float EPS_V = 1e-6f;

// kvll column map (1152): [k: 0..383 | v: 384..767 | logit_q: 768..959 | logit_k: 960..1151]
// Baug rows:              [Wk: 0..383 | Wv: 384..767 | Wlq: 768..959 | Wlk: 960..1151]

// ---------------- async global->LDS (16B per lane) ----------------
__device__ __forceinline__ void gld_lds16(void* lds, const void* g) {
  __builtin_amdgcn_global_load_lds(
      (const __attribute__((address_space(1))) unsigned int*)g,
      (__attribute__((address_space(3))) unsigned int*)lds, 16, 0, 0);
}

__device__ __forceinline__ float bf2f(short s) {
  union { unsigned u; float f; } cv;
  cv.u = ((unsigned)(unsigned short)s) << 16;
  return cv.f;
}
__device__ __forceinline__ short f2bf_s(float f) {
  const __bf16 b = (__bf16)f;
  return __builtin_bit_cast(short, b);
}
__device__ __forceinline__ f32x4 MF(bf16x8 a, bf16x8 b, f32x4 c) {
  return __builtin_amdgcn_mfma_f32_16x16x32_bf16(a, b, c, 0, 0, 0);
}

// ====== BK=32, 3-buffer, counted-vmcnt bf16 GEMM, C = A[M][K] @ B^T[N][K] ==
// BM=BN=128, 256 thr = 4 waves (2x2), wave 64x64 (4x4 frags), 16 MFMA/iter.
// 3 LDS bufs x 16KB = 48KB -> 3 blocks/CU (3 waves/SIMD). Iter kt: wait
// vmcnt(4) (stage(kt) done, stage(kt+1) in flight), barrier, issue
// stage(kt+2), ds_read frags, MFMA. Waits are pre-satisfied in steady state.
// 2-level XOR swizzle for 64B rows: slot ^= (r&3)^((r>>2)&3) — 2 lanes/quad
// (free); source slot thread-constant (both-sides-or-neither).
// EPI 0: bf16 write. EPI 1: fp32 write + bias. blockIdx.z slices by *Slice.
template<int EPI>
__global__ __launch_bounds__(256, 3) void gemm3b(
    const __bf16* __restrict__ A, const __bf16* __restrict__ Bm,
    void* __restrict__ Cout, const float* __restrict__ bias,
    int M, int Nw, int K,
    size_t aSlice, size_t bSlice, size_t cSlice) {
  extern __shared__ __align__(16) char lds[];   // 3 * 16384
  const int t    = threadIdx.x;
  const int lane = t & 63;
  const int wid  = t >> 6;
  const int wm   = wid >> 1;          // 0..1
  const int wn   = wid & 1;           // 0..1
  const int l15  = lane & 15;
  const int kgq  = lane >> 4;         // 0..3

  const int bz = blockIdx.z;
  const __bf16* Ab = A  + (size_t)bz * aSlice;
  const __bf16* Bb = Bm + (size_t)bz * bSlice;

  // bijective XCD chunk swizzle (m204), per z-slice
  const int gx   = gridDim.x;
  const int nwg  = gx * gridDim.y;
  const int orig = blockIdx.y * gx + blockIdx.x;
  const int qq   = nwg >> 3, rr = nwg & 7;
  const int xcd  = orig & 7, pos = orig >> 3;
  const int id   = (xcd < rr ? xcd*(qq+1) : rr*(qq+1) + (xcd-rr)*qq) + pos;
  const int row0 = (id / gx) * 128, col0 = (id % gx) * 128;

  const int nt = K >> 5;              // K-tiles of 32

  // staging: thread t -> rows r = i*64 + (t>>2) (i=0,1), dest slot (t&3).
  // source slot = dest ^ swz(r), swz(r) = (r&3)^((r>>2)&3); both terms are
  // thread-constant: r&3 = (t>>2)&3, (r>>2)&3 = (t>>4)&3 (i*64 drops out).
  const int sg8 = ((t & 3) ^ ((t >> 2) & 3) ^ ((t >> 4) & 3)) * 8;

  auto stage = [&](int kt) {
    char* buf = lds + (kt % 3) * 16384;
    const size_t kofs = (size_t)kt * 32 + sg8;
    #pragma unroll
    for (int i = 0; i < 2; ++i) {
      const int r = i*64 + (t >> 2);
      gld_lds16(buf + i*4096 + t*16,        Ab + (size_t)(row0 + r) * K + kofs);
      gld_lds16(buf + 8192 + i*4096 + t*16, Bb + (size_t)(col0 + r) * K + kofs);
    }
  };

  f32x4 acc[4][4] = {};
  stage(0);
  if (nt > 1) stage(1);

  for (int kt = 0; kt < nt; ++kt) {
    if (kt < nt - 1) asm volatile("s_waitcnt vmcnt(4)" ::: "memory");
    else             asm volatile("s_waitcnt vmcnt(0)" ::: "memory");
    __builtin_amdgcn_s_barrier();
    __builtin_amdgcn_sched_barrier(0);

    char* buf = lds + (kt % 3) * 16384;
    if (kt + 2 < nt) stage(kt + 2);   // buf (kt+2)%3: readers done in iter kt-1

    bf16x8 af[4], bfr[4];
    #pragma unroll
    for (int mi = 0; mi < 4; ++mi) {
      const int a = wm*64 + mi*16 + l15;
      af[mi] = *(const bf16x8*)(buf + a*64
                  + ((kgq*16) ^ ((((a & 3) ^ ((a >> 2) & 3))) << 4)));
    }
    #pragma unroll
    for (int ni = 0; ni < 4; ++ni) {
      const int b = wn*64 + ni*16 + l15;
      bfr[ni] = *(const bf16x8*)(buf + 8192 + b*64
                  + ((kgq*16) ^ ((((b & 3) ^ ((b >> 2) & 3))) << 4)));
    }
    __builtin_amdgcn_s_setprio(1);
    #pragma unroll
    for (int mi = 0; mi < 4; ++mi)
      #pragma unroll
      for (int ni = 0; ni < 4; ++ni)
        acc[mi][ni] = MF(af[mi], bfr[ni], acc[mi][ni]);
    __builtin_amdgcn_s_setprio(0);
  }

  // epilogue: C/D layout col = l15, row = (lane>>4)*4 + j
  const int cr = (lane >> 4) << 2;
  #pragma unroll
  for (int mi = 0; mi < 4; ++mi) {
    #pragma unroll
    for (int ni = 0; ni < 4; ++ni) {
      const int col = col0 + wn*64 + ni*16 + l15;
      #pragma unroll
      for (int j = 0; j < 4; ++j) {
        const int row = row0 + wm*64 + mi*16 + cr + j;
        const float v = acc[mi][ni][j];
        if (EPI == 1) {
          ((float*)Cout + (size_t)bz*cSlice)[(size_t)row * Nw + col] = v + bias[col];
        } else {
          ((__bf16*)Cout + (size_t)bz*cSlice)[(size_t)row * Nw + col] = (__bf16)v;
        }
      }
    }
  }
}

// ---- combined log-weights: Baug rows 768..1151 = scale * (w @ qkv_w_side) --
__global__ __launch_bounds__(256) void wlog_kernel(
    const float* __restrict__ qkv_w, const float* __restrict__ w,
    __bf16* __restrict__ Baug) {
  const int idx = blockIdx.x * 256 + threadIdx.x;   // 2*192*384
  if (idx >= 2*192*384) return;
  const int d = idx % 384, rs = idx / 384;
  const int side = rs / 192, hm = rs % 192;
  const int h = hm / 24;
  const float* wr = w + (size_t)hm * 48;
  const float* qw = qkv_w + ((size_t)(side*384 + h*48)) * 384 + d;
  float acc = 0.f;
  #pragma unroll
  for (int c = 0; c < 48; ++c)
    acc += wr[c] * qw[(size_t)c * 384];
  Baug[(size_t)(768 + side*192 + hm) * 384 + d] = (__bf16)(acc * SCALE);
}

// ---------------- ktv fused: phi_k from [k|lk], MFMA ktv + ksum ----------
// grid (64 splits, H, B) = 2048 blocks; per wave 64 tokens = 2 steps of 32.
// NO atomics: partial (1152 ktv + 24 ksum) -> ktv_part.
__global__ __launch_bounds__(256) void ktv_fused(
    const __bf16* __restrict__ kvll, float* __restrict__ ktv_part) {
  const int b = blockIdx.z, h = blockIdx.y, sp = blockIdx.x;
  const int t = threadIdx.x, wv = t >> 6, lane = t & 63;
  const int l15 = lane & 15, g = lane >> 4;
  const int bh = b*H_SZ + h;
  __shared__ __align__(16) __bf16 vT[4][48][40];    // [wave][c][tok]
  __shared__ __align__(16) __bf16 phiT[4][24][40];  // [wave][m][tok]
  __shared__ float red[4][1184];                    // 1152 ktv + 24 ksum + pad
  f32x4 acc[2][3] = {};
  f32x4 aks[2] = {};                 // ksum via ones-column MFMA
  const int nbase = sp*256 + wv*64;

  bf16x8 ones{};                     // B-frag: col 0 = all-ones
  if (l15 == 0)
    #pragma unroll
    for (int j = 0; j < 8; ++j) ones[j] = (__bf16)1.0f;

  for (int step = 0; step < 2; ++step) {
    const int n0 = nbase + step*32;
    #pragma unroll
    for (int it = 0; it < 3; ++it) {
      const int task = it*64 + lane;
      const int tk = task / 6, p = task % 6;
      const short8 r = *(const short8*)(kvll + ((size_t)(b*N_SZ) + n0 + tk)*1152
                                            + 384 + h*C_SZ + p*8);
      #pragma unroll
      for (int e = 0; e < 8; ++e)
        vT[wv][p*8 + e][tk] = __builtin_bit_cast(__bf16, (short)r[e]);
    }
    if (lane < 32) {
      const __bf16* row = kvll + ((size_t)(b*N_SZ) + n0 + lane)*1152 + h*C_SZ;
      float ss = 0.f;
      #pragma unroll
      for (int i = 0; i < 6; ++i) {
        const short8 r = *(const short8*)(row + i*8);
        #pragma unroll
        for (int j = 0; j < 8; ++j) { const float f = bf2f(r[j]) * SCALE; ss += f*f; }
      }
      const float hs = 0.5f * ss;
      const __bf16* lk = kvll + ((size_t)(b*N_SZ) + n0 + lane)*1152 + 960 + h*24;
      #pragma unroll
      for (int i = 0; i < 3; ++i) {
        const short8 r = *(const short8*)(lk + i*8);
        #pragma unroll
        for (int j = 0; j < 8; ++j)
          phiT[wv][i*8 + j][lane] = (__bf16)(__expf(bf2f(r[j]) - hs) * RSM);
      }
    }
    const bf16x8 a0 = *(const bf16x8*)(&phiT[wv][l15][g*8]);
    bf16x8 a1{};
    if (l15 < 8) a1 = *(const bf16x8*)(&phiT[wv][16 + l15][g*8]);
    #pragma unroll
    for (int ct = 0; ct < 3; ++ct) {
      const bf16x8 bfr = *(const bf16x8*)(&vT[wv][ct*16 + l15][g*8]);
      acc[0][ct] = MF(a0, bfr, acc[0][ct]);
      acc[1][ct] = MF(a1, bfr, acc[1][ct]);
    }
    aks[0] = MF(a0, ones, aks[0]);
    aks[1] = MF(a1, ones, aks[1]);
  }

  // per-wave partials into red: ktv (col(c)=l15, row(m)=g*4+jj) + ksum tail
  #pragma unroll
  for (int mt = 0; mt < 2; ++mt)
    #pragma unroll
    for (int ct = 0; ct < 3; ++ct)
      #pragma unroll
      for (int jj = 0; jj < 4; ++jj) {
        const int row = mt*16 + g*4 + jj;
        if (row < 24)
          red[wv][row*48 + ct*16 + l15] = acc[mt][ct][jj];
      }
  if (l15 == 0) {
    #pragma unroll
    for (int mt = 0; mt < 2; ++mt)
      #pragma unroll
      for (int jj = 0; jj < 4; ++jj) {
        const int m = mt*16 + g*4 + jj;
        if (m < 24) red[wv][1152 + m] = aks[mt][jj];
      }
  }
  __syncthreads();
  float* outp = ktv_part + ((size_t)bh*64 + sp) * 1184;
  for (int i = t; i < 1176; i += 256)
    outp[i] = red[0][i] + red[1][i] + red[2][i] + red[3][i];
}

// ---- reduce: sum 64 split-partials -> ktv_f [bh][1152], ksum [bh][24] ----
// grid 128 = (bh, quarter): each block sums 296 indices over 64 partials.
__global__ __launch_bounds__(256) void reduce_ktv(
    const float* __restrict__ ktv_part, float* __restrict__ ktv_f,
    float* __restrict__ ksum) {
  const int bh = blockIdx.x >> 2, q = blockIdx.x & 3;
  const int i0 = q * 296;
  const int iend = (i0 + 296 < 1176) ? i0 + 296 : 1176;
  for (int i = i0 + threadIdx.x; i < iend; i += 256) {
    float s = 0.f;
    #pragma unroll 8
    for (int sp = 0; sp < 64; ++sp)
      s += ktv_part[((size_t)bh*64 + sp) * 1184 + i];
    if (i < 1152) ktv_f[bh*1152 + i] = s;
    else          ksum[bh*24 + (i - 1152)] = s;
  }
}

// ---- Gt[b][o][hm] = sum_c ktv[bh][m][c] * proj_w[o][48h+c]  (bf16 out) ----
__global__ __launch_bounds__(256) void gt_kernel(
    const float* __restrict__ ktv_f, const float* __restrict__ proj_w,
    __bf16* __restrict__ Gt) {
  const int idx = blockIdx.x * 256 + threadIdx.x;   // 4*384*192
  if (idx >= 4*384*192) return;
  const int hm = idx % 192, o = (idx / 192) % 384, b = idx / (192*384);
  const int h = hm / 24, m = hm % 24;
  const float* kt = ktv_f + ((size_t)(b*H_SZ + h))*1152 + m*48;
  const float* pw = proj_w + (size_t)o*384 + h*48;
  float acc = 0.f;
  #pragma unroll
  for (int c = 0; c < 48; ++c) acc += kt[c] * pw[c];
  Gt[((size_t)b*384 + o)*192 + hm] = (__bf16)acc;
}

// ---- P'[n][hm] = phi_q / D_h  (phi_q = exp(lq)*RSM; hs_q cancels) --------
__global__ __launch_bounds__(256) void pprime_kernel(
    const __bf16* __restrict__ kvll, const float* __restrict__ ksum,
    __bf16* __restrict__ Pp) {
  const int tok = blockIdx.x * 256 + threadIdx.x;
  const int b = (blockIdx.x * 256) >> 14;
  __shared__ float ksl[192];
  if (threadIdx.x < 192) ksl[threadIdx.x] = ksum[b*192 + threadIdx.x];
  __syncthreads();

  const __bf16* lq = kvll + (size_t)tok*1152 + 768;
  __bf16* po = Pp + (size_t)tok*192;
  #pragma unroll
  for (int h = 0; h < 8; ++h) {
    float ph[24];
    float d = EPS_V;
    #pragma unroll
    for (int i = 0; i < 3; ++i) {
      const short8 r = *(const short8*)(lq + h*24 + i*8);
      #pragma unroll
      for (int j = 0; j < 8; ++j) {
        const float p = __expf(bf2f(r[j])) * RSM;
        ph[i*8 + j] = p;
        d += p * ksl[h*24 + i*8 + j];
      }
    }
    const float inv = 1.0f / d;
    #pragma unroll
    for (int i = 0; i < 3; ++i) {
      short8 pk;
      #pragma unroll
      for (int j = 0; j < 8; ++j) pk[j] = f2bf_s(ph[i*8 + j] * inv);
      *(short8*)(po + h*24 + i*8) = pk;
    }
  }
}

// ---------------- fp32 -> bf16 convert ----------------
__global__ __launch_bounds__(256) void f32_to_bf16_kernel(
    const float* __restrict__ in, __bf16* __restrict__ out, int n8) {
  const int i = blockIdx.x * blockDim.x + threadIdx.x;
  if (i >= n8) return;
  const f32x4v a = *(const f32x4v*)(in + (size_t)i*8);
  const f32x4v c = *(const f32x4v*)(in + (size_t)i*8 + 4);
  short8 pk;
  #pragma unroll
  for (int j = 0; j < 4; ++j) {
    pk[j]     = f2bf_s(a[j]);
    pk[4 + j] = f2bf_s(c[j]);
  }
  *(short8*)(out + (size_t)i*8) = pk;
}

extern "C" void kernel_launch(void* const* d_in, const int* in_sizes, int n_in,
                              void* d_out, int out_size, void* d_ws, size_t ws_size,
                              hipStream_t stream) {
  (void)in_sizes; (void)n_in; (void)out_size; (void)ws_size;
  const float* x      = (const float*)d_in[0];
  const float* qkv_w  = (const float*)d_in[1];
  const float* proj_w = (const float*)d_in[2];
  const float* proj_b = (const float*)d_in[3];
  const float* w      = (const float*)d_in[4];
  float* out = (float*)d_out;

  const size_t BN_TOT = (size_t)B_SZ * N_SZ;           // 65536
  char* ws = (char*)d_ws;
  size_t off = 0;
  auto alloc = [&](size_t bytes) {
    char* p = ws + off;
    off += (bytes + 255) & ~(size_t)255;
    return p;
  };
  __bf16* x_bf     = (__bf16*)alloc(BN_TOT * DIM_SZ * 2);          // 50.3 MB
  __bf16* Baug     = (__bf16*)alloc((size_t)1152 * 384 * 2);       // 0.88 MB
  __bf16* kvll     = (__bf16*)alloc(BN_TOT * 1152 * 2);            // 151 MB
  float*  ktv_part = (float*)alloc((size_t)32 * 64 * 1184 * 4);    // 9.7 MB
  float*  ktv_f    = (float*)alloc((size_t)32 * 1152 * 4);
  float*  ksum     = (float*)alloc((size_t)32 * 24 * 4);
  __bf16* Pp       = (__bf16*)alloc(BN_TOT * 192 * 2);             // 25.2 MB
  __bf16* Gt       = (__bf16*)alloc((size_t)B_SZ * 384 * 192 * 2); // 0.6 MB

  static const int LDS3B = 3 * 16384;    // 48 KB
  hipFuncSetAttribute(reinterpret_cast<const void*>(&gemm3b<0>),
                      hipFuncAttributeMaxDynamicSharedMemorySize, LDS3B);
  hipFuncSetAttribute(reinterpret_cast<const void*>(&gemm3b<1>),
                      hipFuncAttributeMaxDynamicSharedMemorySize, LDS3B);

  // conversions + combined weights
  {
    const int n8x = (int)(BN_TOT * DIM_SZ / 8);
    f32_to_bf16_kernel<<<(n8x + 255)/256, 256, 0, stream>>>(x, x_bf, n8x);
    // Baug rows 0..767 = [Wk | Wv] (qkv_w rows 384..1151)
    const int n8kv = 768 * 384 / 8;
    f32_to_bf16_kernel<<<(n8kv + 255)/256, 256, 0, stream>>>(
        qkv_w + (size_t)384 * 384, Baug, n8kv);
    // Baug rows 768..1151 = scale * (w @ qkv_w_{q,k})
    wlog_kernel<<<(2*192*384 + 255)/256, 256, 0, stream>>>(qkv_w, w, Baug);
  }

  // kvll = x @ Baug.T : [k | v | lq | lk]   (65536 x 1152 x 384)
  gemm3b<0><<<dim3(1152/128, BN_TOT/128, 1), 256, LDS3B, stream>>>(
      x_bf, Baug, kvll, nullptr, (int)BN_TOT, 1152, DIM_SZ, 0, 0, 0);

  // ktv + ksum partials (phi_k from k + lk), then reduce (no atomics)
  ktv_fused<<<dim3(64, H_SZ, B_SZ), 256, 0, stream>>>(kvll, ktv_part);
  reduce_ktv<<<128, 256, 0, stream>>>(ktv_part, ktv_f, ksum);

  // Gt = ktv @ proj_w^T (per batch), P' = phi_q / D
  gt_kernel<<<(4*384*192 + 255)/256, 256, 0, stream>>>(ktv_f, proj_w, Gt);
  pprime_kernel<<<(int)(BN_TOT/256), 256, 0, stream>>>(kvll, ksum, Pp);

  // out = P' @ Gt^T + bias   (4 x [16384 x 384 x 192])
  gemm3b<1><<<dim3(384/128, N_SZ/128, B_SZ), 256, LDS3B, stream>>>(
      Pp, Gt, out, proj_b, N_SZ, 384, 192,
      (size_t)N_SZ * 192, (size_t)384 * 192, (size_t)N_SZ * 384);
}

// Round 14
// 189.408 us; speedup vs baseline: 1.0979x; 1.0979x over previous
//
#include <hip/hip_runtime.h>
#include <hip/hip_bf16.h>

typedef __bf16 bf16x8 __attribute__((ext_vector_type(8)));
typedef float  f32x4  __attribute__((ext_vector_type(4)));
typedef short  short8 __attribute__((ext_vector_type(8)));
typedef float  f32x4v __attribute__((ext_vector_type(4)));

#define B_SZ 4
#define N_SZ 16384
#define DIM_SZ 384
#define H_SZ 8
#define C_SZ 48
#define M_SZ 24

static constexpr float SCALE = 0.37991784282579627f;   // 48^-0.25
static constexpr float RSM   = 0.20412414523193154f;   // 1/sqrt(24)
static constexpr float EPS_V = 1e-6f;

// kvll column map (1152): [k: 0..383 | v: 384..767 | logit_q: 768..959 | logit_k: 960..1151]
// Baug rows:              [Wk: 0..383 | Wv: 384..767 | Wlq: 768..959 | Wlk: 960..1151]

// ---------------- async global->LDS (16B per lane) ----------------
__device__ __forceinline__ void gld_lds16(void* lds, const void* g) {
  __builtin_amdgcn_global_load_lds(
      (const __attribute__((address_space(1))) unsigned int*)g,
      (__attribute__((address_space(3))) unsigned int*)lds, 16, 0, 0);
}

__device__ __forceinline__ float bf2f(short s) {
  union { unsigned u; float f; } cv;
  cv.u = ((unsigned)(unsigned short)s) << 16;
  return cv.f;
}
__device__ __forceinline__ short f2bf_s(float f) {
  const __bf16 b = (__bf16)f;
  return __builtin_bit_cast(short, b);
}
__device__ __forceinline__ f32x4 MF(bf16x8 a, bf16x8 b, f32x4 c) {
  return __builtin_amdgcn_mfma_f32_16x16x32_bf16(a, b, c, 0, 0, 0);
}

// ============ 2-block/CU pipelined bf16 GEMM (round-6 proven: 86us, 0 conflicts)
// BM=BN=128, BK=64, 256 thr = 4 waves (2x2), wave 64x64 (4x4 frags).
// 2 LDS buffers x 32KB = 64KB -> 2 blocks/CU; sibling block covers the
// vmcnt(0) drain. XOR-swizzled LDS (slot^=(r&7)), pre-swizzled global src.
// EPI 0: bf16 write. EPI 1: fp32 write + bias. blockIdx.z slices by *Slice.
template<int EPI>
__global__ __launch_bounds__(256, 2) void gemm2b(
    const __bf16* __restrict__ A, const __bf16* __restrict__ Bm,
    void* __restrict__ Cout, const float* __restrict__ bias,
    int M, int Nw, int K,
    size_t aSlice, size_t bSlice, size_t cSlice) {
  extern __shared__ __align__(16) char lds[];   // 2 * 32768
  const int t    = threadIdx.x;
  const int lane = t & 63;
  const int wid  = t >> 6;
  const int wm   = wid >> 1;
  const int wn   = wid & 1;
  const int l15  = lane & 15;
  const int kgq  = lane >> 4;

  const int bz = blockIdx.z;
  const __bf16* Ab = A  + (size_t)bz * aSlice;
  const __bf16* Bb = Bm + (size_t)bz * bSlice;

  // bijective XCD chunk swizzle (m204), per z-slice
  const int gx   = gridDim.x;
  const int nwg  = gx * gridDim.y;
  const int orig = blockIdx.y * gx + blockIdx.x;
  const int qq   = nwg >> 3, rr = nwg & 7;
  const int xcd  = orig & 7, pos = orig >> 3;
  const int id   = (xcd < rr ? xcd*(qq+1) : rr*(qq+1) + (xcd-rr)*qq) + pos;
  const int row0 = (id / gx) * 128, col0 = (id % gx) * 128;

  const int nt = K >> 6;
  const int sg = (t & 7) ^ ((t >> 3) & 7);

  auto stage = [&](int kt) {
    char* buf = lds + (kt & 1) * 32768;
    const size_t kofs = (size_t)kt * 64 + sg * 8;
    #pragma unroll
    for (int i = 0; i < 4; ++i) {
      const int r = i*32 + (t >> 3);
      gld_lds16(buf + i*4096 + t*16,         Ab + (size_t)(row0 + r) * K + kofs);
      gld_lds16(buf + 16384 + i*4096 + t*16, Bb + (size_t)(col0 + r) * K + kofs);
    }
  };

  f32x4 acc[4][4] = {};
  stage(0);

  for (int kt = 0; kt < nt; ++kt) {
    asm volatile("s_waitcnt vmcnt(0)" ::: "memory");
    __builtin_amdgcn_s_barrier();
    __builtin_amdgcn_sched_barrier(0);

    char* buf = lds + (kt & 1) * 32768;
    if (kt + 1 < nt) stage(kt + 1);

    bf16x8 bfr[4][2];
    #pragma unroll
    for (int ni = 0; ni < 4; ++ni) {
      const int brow = wn*64 + ni*16 + l15;
      #pragma unroll
      for (int kk = 0; kk < 2; ++kk)
        bfr[ni][kk] = *(const bf16x8*)(buf + 16384 + brow*128
                          + ((kk*64 + kgq*16) ^ ((brow & 7) << 4)));
    }
    #pragma unroll
    for (int mi = 0; mi < 4; ++mi) {
      const int arow = wm*64 + mi*16 + l15;
      const bf16x8 a0 = *(const bf16x8*)(buf + arow*128
                          + ((kgq*16)      ^ ((arow & 7) << 4)));
      const bf16x8 a1 = *(const bf16x8*)(buf + arow*128
                          + ((64 + kgq*16) ^ ((arow & 7) << 4)));
      __builtin_amdgcn_s_setprio(1);
      #pragma unroll
      for (int ni = 0; ni < 4; ++ni) {
        acc[mi][ni] = MF(a0, bfr[ni][0], acc[mi][ni]);
        acc[mi][ni] = MF(a1, bfr[ni][1], acc[mi][ni]);
      }
      __builtin_amdgcn_s_setprio(0);
    }
  }

  const int cr = (lane >> 4) << 2;
  #pragma unroll
  for (int mi = 0; mi < 4; ++mi) {
    #pragma unroll
    for (int ni = 0; ni < 4; ++ni) {
      const int col = col0 + wn*64 + ni*16 + l15;
      #pragma unroll
      for (int j = 0; j < 4; ++j) {
        const int row = row0 + wm*64 + mi*16 + cr + j;
        const float v = acc[mi][ni][j];
        if (EPI == 1) {
          ((float*)Cout + (size_t)bz*cSlice)[(size_t)row * Nw + col] = v + bias[col];
        } else {
          ((__bf16*)Cout + (size_t)bz*cSlice)[(size_t)row * Nw + col] = (__bf16)v;
        }
      }
    }
  }
}

// ---- prep: x->bf16 | qkv_w kv rows ->Baug | wlog ->Baug (one launch) ----
// blocks [0,12288): x; [12288,12432): kv convert; [12432,13008): wlog.
__global__ __launch_bounds__(256) void prep_kernel(
    const float* __restrict__ x, const float* __restrict__ qkv_w,
    const float* __restrict__ w, __bf16* __restrict__ x_bf,
    __bf16* __restrict__ Baug) {
  const int bid = blockIdx.x, t = threadIdx.x;
  if (bid < 12288) {                      // x: 65536*384/8 = 3145728 groups
    const int i = bid * 256 + t;
    const f32x4v a = *(const f32x4v*)(x + (size_t)i*8);
    const f32x4v c = *(const f32x4v*)(x + (size_t)i*8 + 4);
    short8 pk;
    #pragma unroll
    for (int j = 0; j < 4; ++j) {
      pk[j]     = f2bf_s(a[j]);
      pk[4 + j] = f2bf_s(c[j]);
    }
    *(short8*)(x_bf + (size_t)i*8) = pk;
  } else if (bid < 12432) {               // kv: 768*384/8 = 36864 groups
    const int i = (bid - 12288) * 256 + t;
    const float* src = qkv_w + (size_t)384 * 384;
    const f32x4v a = *(const f32x4v*)(src + (size_t)i*8);
    const f32x4v c = *(const f32x4v*)(src + (size_t)i*8 + 4);
    short8 pk;
    #pragma unroll
    for (int j = 0; j < 4; ++j) {
      pk[j]     = f2bf_s(a[j]);
      pk[4 + j] = f2bf_s(c[j]);
    }
    *(short8*)(Baug + (size_t)i*8) = pk;
  } else {                                // wlog: 2*192*384 = 147456 elems
    const int idx = (bid - 12432) * 256 + t;
    const int d = idx % 384, rs = idx / 384;
    const int side = rs / 192, hm = rs % 192;
    const int h = hm / 24;
    const float* wr = w + (size_t)hm * 48;
    const float* qw = qkv_w + ((size_t)(side*384 + h*48)) * 384 + d;
    float acc = 0.f;
    #pragma unroll
    for (int c = 0; c < 48; ++c)
      acc += wr[c] * qw[(size_t)c * 384];
    Baug[(size_t)(768 + side*192 + hm) * 384 + d] = (__bf16)(acc * SCALE);
  }
}

// ---------------- ktv fused v2: coalesced k/lk staging via LDS ----------
// grid (64 splits, H, B) = 2048 blocks; per wave 64 tokens = 2 steps of 32.
// All global reads are task-coalesced 16B chunks (v transposed to vT; k->kS,
// lk->lkS row-wise, 16B-aligned padded rows). hs/phi computed from LDS.
// NO atomics: partial (1152 ktv + 24 ksum) -> ktv_part.
__global__ __launch_bounds__(256) void ktv_fused(
    const __bf16* __restrict__ kvll, float* __restrict__ ktv_part) {
  const int b = blockIdx.z, h = blockIdx.y, sp = blockIdx.x;
  const int t = threadIdx.x, wv = t >> 6, lane = t & 63;
  const int l15 = lane & 15, g = lane >> 4;
  const int bh = b*H_SZ + h;

  __shared__ __align__(16) char smem[47616];
  __bf16 (*vT)[48][40]  = (__bf16(*)[48][40])(smem);            // 15360 B
  __bf16 (*phiT)[24][40]= (__bf16(*)[24][40])(smem + 15360);    //  7680 B
  __bf16 (*kS)[32][56]  = (__bf16(*)[32][56])(smem + 23040);    // 14336 B
  __bf16 (*lkS)[32][40] = (__bf16(*)[32][40])(smem + 37376);    // 10240 B
  float  (*red)[1184]   = (float(*)[1184])(smem);               // reuse (18944 B)

  f32x4 acc[2][3] = {};
  f32x4 aks[2] = {};                 // ksum via ones-column MFMA
  const int nbase = sp*256 + wv*64;

  bf16x8 ones{};                     // B-frag: col 0 = all-ones
  if (l15 == 0)
    #pragma unroll
    for (int j = 0; j < 8; ++j) ones[j] = (__bf16)1.0f;

  for (int step = 0; step < 2; ++step) {
    const int n0 = nbase + step*32;
    const __bf16* base = kvll + ((size_t)(b*N_SZ) + n0) * 1152;
    // ---- stage v (transposed), k, lk: all task-coalesced 16B chunks ----
    #pragma unroll
    for (int it = 0; it < 3; ++it) {     // v: 192 tasks (32 tok x 6 pieces)
      const int task = it*64 + lane;
      const int tk = task / 6, p = task % 6;
      const short8 r = *(const short8*)(base + (size_t)tk*1152 + 384 + h*C_SZ + p*8);
      #pragma unroll
      for (int e = 0; e < 8; ++e)
        vT[wv][p*8 + e][tk] = __builtin_bit_cast(__bf16, (short)r[e]);
    }
    #pragma unroll
    for (int it = 0; it < 3; ++it) {     // k: 192 tasks -> kS rows
      const int task = it*64 + lane;
      const int tk = task / 6, p = task % 6;
      const short8 r = *(const short8*)(base + (size_t)tk*1152 + h*C_SZ + p*8);
      *(short8*)(&kS[wv][tk][p*8]) = r;
    }
    {                                    // lk: 96 tasks (32 tok x 3 pieces)
      const int task0 = lane;
      {
        const int tk = task0 / 3, p = task0 % 3;
        const short8 r = *(const short8*)(base + (size_t)tk*1152 + 960 + h*24 + p*8);
        *(short8*)(&lkS[wv][tk][p*8]) = r;
      }
      if (lane < 32) {
        const int task = 64 + lane;
        const int tk = task / 3, p = task % 3;
        const short8 r = *(const short8*)(base + (size_t)tk*1152 + 960 + h*24 + p*8);
        *(short8*)(&lkS[wv][tk][p*8]) = r;
      }
    }
    // ---- hs + phi from LDS (lanes < 32, own token row) ----
    if (lane < 32) {
      float ss = 0.f;
      #pragma unroll
      for (int i = 0; i < 6; ++i) {
        const short8 r = *(const short8*)(&kS[wv][lane][i*8]);
        #pragma unroll
        for (int j = 0; j < 8; ++j) { const float f = bf2f(r[j]) * SCALE; ss += f*f; }
      }
      const float hs = 0.5f * ss;
      #pragma unroll
      for (int i = 0; i < 3; ++i) {
        const short8 r = *(const short8*)(&lkS[wv][lane][i*8]);
        #pragma unroll
        for (int j = 0; j < 8; ++j)
          phiT[wv][i*8 + j][lane] = (__bf16)(__expf(bf2f(r[j]) - hs) * RSM);
      }
    }
    // ---- MFMA: ktv[m][c] += phi[m][tok] * vT[c][tok]; ksum via ones ----
    const bf16x8 a0 = *(const bf16x8*)(&phiT[wv][l15][g*8]);
    bf16x8 a1{};
    if (l15 < 8) a1 = *(const bf16x8*)(&phiT[wv][16 + l15][g*8]);
    #pragma unroll
    for (int ct = 0; ct < 3; ++ct) {
      const bf16x8 bfr = *(const bf16x8*)(&vT[wv][ct*16 + l15][g*8]);
      acc[0][ct] = MF(a0, bfr, acc[0][ct]);
      acc[1][ct] = MF(a1, bfr, acc[1][ct]);
    }
    aks[0] = MF(a0, ones, aks[0]);
    aks[1] = MF(a1, ones, aks[1]);
  }

  __syncthreads();   // all waves done with vT/phiT/kS/lkS before red reuse

  // per-wave partials into red: ktv (col(c)=l15, row(m)=g*4+jj) + ksum tail
  #pragma unroll
  for (int mt = 0; mt < 2; ++mt)
    #pragma unroll
    for (int ct = 0; ct < 3; ++ct)
      #pragma unroll
      for (int jj = 0; jj < 4; ++jj) {
        const int row = mt*16 + g*4 + jj;
        if (row < 24)
          red[wv][row*48 + ct*16 + l15] = acc[mt][ct][jj];
      }
  if (l15 == 0) {
    #pragma unroll
    for (int mt = 0; mt < 2; ++mt)
      #pragma unroll
      for (int jj = 0; jj < 4; ++jj) {
        const int m = mt*16 + g*4 + jj;
        if (m < 24) red[wv][1152 + m] = aks[mt][jj];
      }
  }
  __syncthreads();
  float* outp = ktv_part + ((size_t)bh*64 + sp) * 1184;
  for (int i = t; i < 1176; i += 256)
    outp[i] = red[0][i] + red[1][i] + red[2][i] + red[3][i];
}

// ---- reduce: sum 64 split-partials -> ktv_f [bh][1152], ksum [bh][24] ----
// grid 128 = (bh, quarter): each block sums 296 indices over 64 partials.
__global__ __launch_bounds__(256) void reduce_ktv(
    const float* __restrict__ ktv_part, float* __restrict__ ktv_f,
    float* __restrict__ ksum) {
  const int bh = blockIdx.x >> 2, q = blockIdx.x & 3;
  const int i0 = q * 296;
  const int iend = (i0 + 296 < 1176) ? i0 + 296 : 1176;
  for (int i = i0 + threadIdx.x; i < iend; i += 256) {
    float s = 0.f;
    #pragma unroll 8
    for (int sp = 0; sp < 64; ++sp)
      s += ktv_part[((size_t)bh*64 + sp) * 1184 + i];
    if (i < 1152) ktv_f[bh*1152 + i] = s;
    else          ksum[bh*24 + (i - 1152)] = s;
  }
}

// ---- merged: Gt (blocks 0..1151) + P' (blocks 1152..1407) ----------------
__global__ __launch_bounds__(256) void gtpp_kernel(
    const float* __restrict__ ktv_f, const float* __restrict__ proj_w,
    const __bf16* __restrict__ kvll, const float* __restrict__ ksum,
    __bf16* __restrict__ Gt, __bf16* __restrict__ Pp) {
  const int bid = blockIdx.x, t = threadIdx.x;
  if (bid < 1152) {
    // Gt[b][o][hm] = sum_c ktv[bh][m][c] * proj_w[o][48h+c]
    const int idx = bid * 256 + t;        // 4*384*192
    const int hm = idx % 192, o = (idx / 192) % 384, b = idx / (192*384);
    const int h = hm / 24, m = hm % 24;
    const float* kt = ktv_f + ((size_t)(b*H_SZ + h))*1152 + m*48;
    const float* pw = proj_w + (size_t)o*384 + h*48;
    float acc = 0.f;
    #pragma unroll
    for (int c = 0; c < 48; ++c) acc += kt[c] * pw[c];
    Gt[((size_t)b*384 + o)*192 + hm] = (__bf16)acc;
    return;
  }
  // P'[n][hm] = phi_q / D_h  (phi_q = exp(lq)*RSM; hs_q cancels)
  const int blk = bid - 1152;
  const int tok = blk * 256 + t;
  const int b = (blk * 256) >> 14;
  __shared__ float ksl[192];
  if (t < 192) ksl[t] = ksum[b*192 + t];
  __syncthreads();

  const __bf16* lq = kvll + (size_t)tok*1152 + 768;
  __bf16* po = Pp + (size_t)tok*192;
  #pragma unroll
  for (int h = 0; h < 8; ++h) {
    float ph[24];
    float d = EPS_V;
    #pragma unroll
    for (int i = 0; i < 3; ++i) {
      const short8 r = *(const short8*)(lq + h*24 + i*8);
      #pragma unroll
      for (int j = 0; j < 8; ++j) {
        const float p = __expf(bf2f(r[j])) * RSM;
        ph[i*8 + j] = p;
        d += p * ksl[h*24 + i*8 + j];
      }
    }
    const float inv = 1.0f / d;
    #pragma unroll
    for (int i = 0; i < 3; ++i) {
      short8 pk;
      #pragma unroll
      for (int j = 0; j < 8; ++j) pk[j] = f2bf_s(ph[i*8 + j] * inv);
      *(short8*)(po + h*24 + i*8) = pk;
    }
  }
}

extern "C" void kernel_launch(void* const* d_in, const int* in_sizes, int n_in,
                              void* d_out, int out_size, void* d_ws, size_t ws_size,
                              hipStream_t stream) {
  (void)in_sizes; (void)n_in; (void)out_size; (void)ws_size;
  const float* x      = (const float*)d_in[0];
  const float* qkv_w  = (const float*)d_in[1];
  const float* proj_w = (const float*)d_in[2];
  const float* proj_b = (const float*)d_in[3];
  const float* w      = (const float*)d_in[4];
  float* out = (float*)d_out;

  const size_t BN_TOT = (size_t)B_SZ * N_SZ;           // 65536
  char* ws = (char*)d_ws;
  size_t off = 0;
  auto alloc = [&](size_t bytes) {
    char* p = ws + off;
    off += (bytes + 255) & ~(size_t)255;
    return p;
  };
  __bf16* x_bf     = (__bf16*)alloc(BN_TOT * DIM_SZ * 2);          // 50.3 MB
  __bf16* Baug     = (__bf16*)alloc((size_t)1152 * 384 * 2);       // 0.88 MB
  __bf16* kvll     = (__bf16*)alloc(BN_TOT * 1152 * 2);            // 151 MB
  float*  ktv_part = (float*)alloc((size_t)32 * 64 * 1184 * 4);    // 9.7 MB
  float*  ktv_f    = (float*)alloc((size_t)32 * 1152 * 4);
  float*  ksum     = (float*)alloc((size_t)32 * 24 * 4);
  __bf16* Pp       = (__bf16*)alloc(BN_TOT * 192 * 2);             // 25.2 MB
  __bf16* Gt       = (__bf16*)alloc((size_t)B_SZ * 384 * 192 * 2); // 0.6 MB

  static const int LDS2B = 2 * 32768;    // 64 KB double buffer
  hipFuncSetAttribute(reinterpret_cast<const void*>(&gemm2b<0>),
                      hipFuncAttributeMaxDynamicSharedMemorySize, LDS2B);
  hipFuncSetAttribute(reinterpret_cast<const void*>(&gemm2b<1>),
                      hipFuncAttributeMaxDynamicSharedMemorySize, LDS2B);

  // prep: x convert + Baug build (one launch)
  prep_kernel<<<13008, 256, 0, stream>>>(x, qkv_w, w, x_bf, Baug);

  // kvll = x @ Baug.T : [k | v | lq | lk]   (65536 x 1152 x 384)
  gemm2b<0><<<dim3(1152/128, BN_TOT/128, 1), 256, LDS2B, stream>>>(
      x_bf, Baug, kvll, nullptr, (int)BN_TOT, 1152, DIM_SZ, 0, 0, 0);

  // ktv + ksum partials (phi_k from k + lk), then reduce (no atomics)
  ktv_fused<<<dim3(64, H_SZ, B_SZ), 256, 0, stream>>>(kvll, ktv_part);
  reduce_ktv<<<128, 256, 0, stream>>>(ktv_part, ktv_f, ksum);

  // Gt = ktv @ proj_w^T + P' = phi_q / D (one launch)
  gtpp_kernel<<<1408, 256, 0, stream>>>(ktv_f, proj_w, kvll, ksum, Gt, Pp);

  // out = P' @ Gt^T + bias   (4 x [16384 x 384 x 192])
  gemm2b<1><<<dim3(384/128, N_SZ/128, B_SZ), 256, LDS2B, stream>>>(
      Pp, Gt, out, proj_b, N_SZ, 384, 192,
      (size_t)N_SZ * 192, (size_t)384 * 192, (size_t)N_SZ * 384);
}